// Round 6
// baseline (214.089 us; speedup 1.0000x reference)
//
#include <hip/hip_runtime.h>
#include <cmath>
#include <cstdint>

#define NB 32
#define NP 24564
#define NC 81
#define NEG_POS 3

static constexpr size_t MINED_ELEMS = (size_t)NB * NP;             // 786,048
static constexpr size_t MINED_BYTES = MINED_ELEMS * sizeof(float); // 3,144,192

// mb_main geometry: wave-private double-buffered LDS pipeline, small chunks
// for high occupancy. CH=8 rows/chunk -> 2592 B/buffer; 4 waves * 2 buffers
// = 20.7 KB/block -> 7 blocks/CU (LDS), 6 waves/SIMD (VGPR cap) = 24 waves/CU.
#define CH 8                        // rows per chunk
#define CH_DW (CH * NC)             // 648 dwords = 2592 B
#define CH_F4 (CH_DW / 4)           // 162 float4
#define SLOADS 3                    // ceil(162/64)
#define CHUNKS_PER_WAVE 8
#define ROWS_PER_WAVE (CH * CHUNKS_PER_WAVE)    // 64
#define WAVES_PER_B ((NP + ROWS_PER_WAVE - 1) / ROWS_PER_WAVE)  // 384
#define TOTAL_WAVES (NB * WAVES_PER_B)          // 12288
#define MAIN_BLOCKS (TOTAL_WAVES / 4)           // 3072

// ws layout:
//   [0, MINED_BYTES)                    float mined[NB*NP]
//   [MINED_BYTES, +24)                  double acc[3]  {loc_loss, ce_pos_sum, neg_sum}
//   [MINED_BYTES+24, +24+4*NB)          int   num_pos[NB]

__device__ __forceinline__ float wave_reduce_sum(float v) {
#pragma unroll
  for (int off = 32; off > 0; off >>= 1) v += __shfl_down(v, off, 64);
  return v;
}

__device__ __forceinline__ float smooth_l1_4(float4 a, float4 t) {
  float acc = 0.f, d, ax;
  d = a.x - t.x; ax = fabsf(d); acc += (ax < 1.f) ? 0.5f * d * d : ax - 0.5f;
  d = a.y - t.y; ax = fabsf(d); acc += (ax < 1.f) ? 0.5f * d * d : ax - 0.5f;
  d = a.z - t.z; ax = fabsf(d); acc += (ax < 1.f) ? 0.5f * d * d : ax - 0.5f;
  d = a.w - t.w; ax = fabsf(d); acc += (ax < 1.f) ? 0.5f * d * d : ax - 0.5f;
  return acc;
}

__global__ void mb_init(double* __restrict__ acc, int* __restrict__ num_pos) {
  int t = threadIdx.x;
  if (t < 3) acc[t] = 0.0;
  if (t < NB) num_pos[t] = 0;
}

// Each wave owns 64 rows (8 chunks of 8). Lane = row(3b low) + part(3b high);
// part p sums classes [10p, 10p+10) (part 7 gets 11). Target logit gathered
// directly from LDS by the row lane. Next-chunk loads stay in flight across
// the compute phase (issue-early / write-late).
__global__ __launch_bounds__(256, 6) void mb_main(
    const float* __restrict__ loc_data, const float* __restrict__ conf_data,
    const float* __restrict__ loc_targets, const int* __restrict__ conf_targets,
    float* __restrict__ mined, double* __restrict__ acc, int* __restrict__ num_pos) {
  const int wid  = (int)threadIdx.x >> 6;
  const int lane = (int)threadIdx.x & 63;
  const int W = blockIdx.x * 4 + wid;          // global wave id
  const int b = W / WAVES_PER_B;               // 384 % 4 == 0 -> all 4 waves share b
  const int wslot = W - b * WAVES_PER_B;
  const size_t bbase = (size_t)b * NP;
  const int prow0 = wslot * ROWS_PER_WAVE;

  __shared__ float lds[4][2][CH_DW];           // 20,736 B

  const int row  = lane & 7;
  const int part = lane >> 3;

  float loc_v = 0.f, ce_pos = 0.f, pcnt = 0.f;

  float4 r[SLOADS];
  int tgt_cur = 0, tgt_nxt = 0;

  // ---- prologue: stage chunk 0 into buffer 0 ----
  {
    const int n = (NP - prow0 < CH) ? (NP - prow0) : CH;   // 8 or 4
    const int nq = (n * NC) >> 2;                           // exact (n%4==0)
    const float4* s4 =
        reinterpret_cast<const float4*>(conf_data + (bbase + prow0) * (size_t)NC);
#pragma unroll
    for (int i = 0; i < SLOADS; ++i) {
      const int q = i * 64 + lane;
      if (q < nq) r[i] = s4[q];
    }
    tgt_cur = (lane < n) ? conf_targets[bbase + prow0 + lane] : 0;
    float* dst = &lds[wid][0][0];
#pragma unroll
    for (int i = 0; i < SLOADS; ++i) {
      const int q = i * 64 + lane;
      if (q < nq) reinterpret_cast<float4*>(dst)[q] = r[i];
    }
  }

  for (int t = 0; t < CHUNKS_PER_WAVE; ++t) {
    const int cur = t & 1;
    const int p0 = prow0 + t * CH;
    const int n = (NP - p0 < CH) ? (NP - p0) : CH;
    if (n <= 0) break;

    // ---- issue next-chunk loads (in flight through compute) ----
    const int pn = p0 + CH;
    const int nn = (NP - pn < CH) ? (NP - pn) : CH;
    if (t < CHUNKS_PER_WAVE - 1 && nn > 0) {
      const int nq = (nn * NC) >> 2;
      const float4* s4 =
          reinterpret_cast<const float4*>(conf_data + (bbase + pn) * (size_t)NC);
#pragma unroll
      for (int i = 0; i < SLOADS; ++i) {
        const int q = i * 64 + lane;
        if (q < nq) r[i] = s4[q];
      }
      tgt_nxt = (lane < nn) ? conf_targets[bbase + pn + lane] : 0;
    }
    __builtin_amdgcn_sched_barrier(0);  // loads above; compute below

    // ---- compute chunk t from lds[wid][cur] ----
    {
      const float* base = &lds[wid][cur][0];
      const float* rp = base + row * NC + part * 10;
      float s = 0.f;
#pragma unroll
      for (int j = 0; j < 10; ++j) s += __expf(rp[j]);
      if (part == 7) s += __expf(rp[10]);   // class 80
      s += __shfl_xor(s, 8, 64);
      s += __shfl_xor(s, 16, 64);
      s += __shfl_xor(s, 32, 64);

      if (lane < n) {                        // part==0, row==lane
        const int tgt = tgt_cur;
        const float tv = base[lane * NC + tgt];   // direct LDS gather
        const float ce = __logf(s) - tv;     // unstabilized LSE safe: |x| < ~6
        const int is_pos = tgt > 0;
        const size_t idx = bbase + p0 + lane;
        mined[idx] = is_pos ? 0.f : ce;      // ce > 0 always; bits order as floats
        if (is_pos) {
          pcnt += 1.f;
          ce_pos += ce;
          loc_v += smooth_l1_4(*reinterpret_cast<const float4*>(loc_data + idx * 4),
                               *reinterpret_cast<const float4*>(loc_targets + idx * 4));
        }
      }
    }
    __builtin_amdgcn_sched_barrier(0);  // ds_write (and its vmcnt wait) below

    // ---- write next chunk to the other buffer ----
    if (t < CHUNKS_PER_WAVE - 1 && nn > 0) {
      const int nq = (nn * NC) >> 2;
      float* dst = &lds[wid][cur ^ 1][0];
#pragma unroll
      for (int i = 0; i < SLOADS; ++i) {
        const int q = i * 64 + lane;
        if (q < nq) reinterpret_cast<float4*>(dst)[q] = r[i];
      }
      tgt_cur = tgt_nxt;
    }
  }

  // ---- block reduction (all 4 waves share b) ----
  __shared__ float red[3][4];
  float r0 = wave_reduce_sum(loc_v);
  float r1 = wave_reduce_sum(ce_pos);
  float r2 = wave_reduce_sum(pcnt);
  if (lane == 0) { red[0][wid] = r0; red[1][wid] = r1; red[2][wid] = r2; }
  __syncthreads();
  if (threadIdx.x == 0) {
    float t0 = 0.f, t1 = 0.f, t2 = 0.f;
#pragma unroll
    for (int i = 0; i < 4; ++i) { t0 += red[0][i]; t1 += red[1][i]; t2 += red[2][i]; }
    if (t0 != 0.f) atomicAdd(&acc[0], (double)t0);
    if (t1 != 0.f) atomicAdd(&acc[1], (double)t1);
    const int np = (int)t2;
    if (np) atomicAdd(&num_pos[b], np);
  }
}

// One block per batch row: radix-select the (k+1)-th largest of mined[b,:]
// (k = min(3*num_pos, NP-1)), then sum elements strictly greater.
__global__ __launch_bounds__(1024) void mb_select(
    const float* __restrict__ mined, const int* __restrict__ num_pos,
    double* __restrict__ acc) {
  const int b = blockIdx.x;
  const float* __restrict__ row = mined + (size_t)b * NP;
  const int tid = threadIdx.x;
  const int wid = tid >> 6;  // 16 waves

  __shared__ int hist[16][256];   // per-wave histograms (16 KB)
  __shared__ int total[256];
  __shared__ int suffix[256];
  __shared__ unsigned s_prefix;
  __shared__ int s_k;

  if (tid == 0) {
    int k = NEG_POS * num_pos[b];
    if (k > NP - 1) k = NP - 1;
    s_k = k;          // 0-indexed rank, descending order
    s_prefix = 0u;
  }
  __syncthreads();

  for (int shift = 24; shift >= 0; shift -= 8) {
    for (int i = tid; i < 16 * 256; i += 1024) ((int*)hist)[i] = 0;
    __syncthreads();
    const unsigned mask = (shift == 24) ? 0u : (0xFFFFFFFFu << (shift + 8));
    const unsigned pfx = s_prefix;
    const int kcur = s_k;

    for (int q = tid; q < NP / 4; q += 1024) {
      const float4 v = reinterpret_cast<const float4*>(row)[q];
      unsigned u;
      u = __float_as_uint(v.x); if ((u & mask) == pfx) atomicAdd(&hist[wid][(u >> shift) & 255], 1);
      u = __float_as_uint(v.y); if ((u & mask) == pfx) atomicAdd(&hist[wid][(u >> shift) & 255], 1);
      u = __float_as_uint(v.z); if ((u & mask) == pfx) atomicAdd(&hist[wid][(u >> shift) & 255], 1);
      u = __float_as_uint(v.w); if ((u & mask) == pfx) atomicAdd(&hist[wid][(u >> shift) & 255], 1);
    }
    __syncthreads();

    if (tid < 256) {
      int t = 0;
#pragma unroll
      for (int w = 0; w < 16; ++w) t += hist[w][tid];
      total[tid] = t;
      suffix[tid] = t;
    }
    __syncthreads();
    for (int d = 1; d < 256; d <<= 1) {
      int v = 0;
      if (tid < 256) {
        v = suffix[tid];
        if (tid + d < 256) v += suffix[tid + d];
      }
      __syncthreads();
      if (tid < 256) suffix[tid] = v;
      __syncthreads();
    }
    if (tid < 256) {
      const int cs = suffix[tid] - total[tid];   // count strictly above this bin
      if (kcur >= cs && kcur < cs + total[tid]) {
        s_prefix = pfx | ((unsigned)tid << shift);
        s_k = kcur - cs;
      }
    }
    __syncthreads();
  }

  const unsigned vbits = s_prefix;  // exact pivot bit pattern
  float sum = 0.f;
  for (int q = tid; q < NP / 4; q += 1024) {
    const float4 v = reinterpret_cast<const float4*>(row)[q];
    if (__float_as_uint(v.x) > vbits) sum += v.x;
    if (__float_as_uint(v.y) > vbits) sum += v.y;
    if (__float_as_uint(v.z) > vbits) sum += v.z;
    if (__float_as_uint(v.w) > vbits) sum += v.w;
  }

  __shared__ float wsum[16];
  float w = wave_reduce_sum(sum);
  if ((tid & 63) == 0) wsum[tid >> 6] = w;
  __syncthreads();
  if (tid == 0) {
    float t = 0.f;
#pragma unroll
    for (int i = 0; i < 16; ++i) t += wsum[i];
    atomicAdd(&acc[2], (double)t);
  }
}

__global__ void mb_finalize(const double* __restrict__ acc,
                            const int* __restrict__ num_pos,
                            float* __restrict__ out) {
  if (threadIdx.x == 0) {
    int tot = 0;
#pragma unroll
    for (int i = 0; i < NB; ++i) tot += num_pos[i];
    const double n = (double)(tot > 0 ? tot : 1);
    out[0] = (float)((acc[0] + acc[1] + acc[2]) / n);
  }
}

extern "C" void kernel_launch(void* const* d_in, const int* in_sizes, int n_in,
                              void* d_out, int out_size, void* d_ws, size_t ws_size,
                              hipStream_t stream) {
  const float* loc_data     = (const float*)d_in[0];
  const float* conf_data    = (const float*)d_in[1];
  const float* loc_targets  = (const float*)d_in[2];
  const int*   conf_targets = (const int*)d_in[3];
  float* out = (float*)d_out;

  float*  mined   = (float*)d_ws;
  double* acc     = (double*)((char*)d_ws + MINED_BYTES);
  int*    num_pos = (int*)((char*)d_ws + MINED_BYTES + 3 * sizeof(double));

  mb_init<<<1, 64, 0, stream>>>(acc, num_pos);

  mb_main<<<MAIN_BLOCKS, 256, 0, stream>>>(loc_data, conf_data, loc_targets,
                                           conf_targets, mined, acc, num_pos);

  mb_select<<<NB, 1024, 0, stream>>>(mined, num_pos, acc);

  mb_finalize<<<1, 64, 0, stream>>>(acc, num_pos, out);
}